// Round 5
// baseline (217.713 us; speedup 1.0000x reference)
//
#include <hip/hip_runtime.h>
#include <math.h>

#define BB 1024
#define NN 4096
#define HH 32
#define PP 4                 // K1 partial blocks per batch
#define RK1 (NN / PP)        // 1024 rows per K1 block
#define T3 512               // K3 threads (8 waves) -> 4 blocks/CU, 32 waves/CU

// ws layout (floats)
#define WS_PART 0            // [BB*PP*HH) column-sum partials

// ---------------- K1: per-batch column-sum partials ----------------
// grid = BB*PP blocks x 256 thr. Pure load stream, full occupancy.
__global__ __launch_bounds__(256) void k1_colsum(
    const float* __restrict__ ne, float* __restrict__ ws)
{
    const int blk = blockIdx.x;
    const int b   = blk >> 2;
    const int p   = blk & (PP - 1);
    const int tid = threadIdx.x;
    const int q8  = tid & 7;     // float4 chunk within row
    const int r   = tid >> 3;    // row offset 0..31

    __shared__ float s_part[256 * 4];

    const float* base = ne + (size_t)b * (NN * HH)
                           + (size_t)(p * RK1 + r) * HH + q8 * 4;
    float a0 = 0.f, a1 = 0.f, a2 = 0.f, a3 = 0.f;
    #pragma unroll 8
    for (int i = 0; i < RK1 / 32; ++i) {               // 32 iters
        const float4 v = *reinterpret_cast<const float4*>(base + i * (32 * HH));
        a0 += v.x; a1 += v.y; a2 += v.z; a3 += v.w;
    }
    *reinterpret_cast<float4*>(&s_part[tid * 4]) = make_float4(a0, a1, a2, a3);
    __syncthreads();

    // deterministic fixed-order reduce: thread h sums its column's 32 partials
    if (tid < HH) {
        const int q = tid >> 2, j = tid & 3;
        float s = 0.f;
        #pragma unroll
        for (int rr = 0; rr < 32; ++rr) s += s_part[(rr * 8 + q) * 4 + j];
        ws[WS_PART + (b * PP + p) * HH + tid] = s;
    }
}

// ---------------- K3: fused MLP + scores + softmax ----------------
// grid = BB blocks x 512 thr, ~17 KB LDS -> 4 blocks/CU (all 1024 resident).
__global__ __launch_bounds__(T3) void k3_scores(
    const float* __restrict__ ne, const float* __restrict__ mask,
    const float* __restrict__ times,
    const float* __restrict__ W1, const float* __restrict__ b1,
    const float* __restrict__ Wq, const float* __restrict__ Wk,
    const int* __restrict__ idxc,
    const float* __restrict__ ws, float* __restrict__ out)
{
    const int b   = blockIdx.x;
    const int tid = threadIdx.x;
    const int q8  = tid & 7;
    const int r   = tid >> 3;    // 0..63

    __shared__ float s_scores[NN];     // 16 KB
    __shared__ float sh_avg[HH], sh_f[HH], sh_emb[HH], sh_qk[HH];
    __shared__ float red_buf[8];

    // ---- prelude: rebuild avg, gather f, tiny MLP -> qk (threads 0..31) ----
    if (tid < HH) {
        float s = 0.f;
        #pragma unroll
        for (int p = 0; p < PP; ++p) s += ws[WS_PART + (b * PP + p) * HH + tid];
        sh_avg[tid] = s * (1.0f / (float)NN);
        sh_f[tid]   = ne[(size_t)b * (NN * HH) + (size_t)idxc[b] * HH + tid];
    }
    __syncthreads();
    if (tid < HH) {
        const float t = times[b];
        const float* w = W1 + tid * (2 * HH + 1);
        float e = b1[tid];
        #pragma unroll
        for (int j = 0; j < HH; ++j) e += sh_avg[j] * w[j];
        #pragma unroll
        for (int j = 0; j < HH; ++j) e += sh_f[j] * w[HH + j];
        e += t * w[2 * HH];
        sh_emb[tid] = e;
    }
    __syncthreads();
    if (tid < HH) {  // q = emb @ Wq^T
        const float* w = Wq + tid * HH;
        float qv = 0.f;
        #pragma unroll
        for (int j = 0; j < HH; ++j) qv += sh_emb[j] * w[j];
        sh_f[tid] = qv;              // reuse sh_f for q
    }
    __syncthreads();
    if (tid < HH) {  // qk[j] = sum_h q[h]*Wk[h,j], scaled 1/sqrt(H)
        float s = 0.f;
        #pragma unroll
        for (int h = 0; h < HH; ++h) s += sh_f[h] * Wk[h * HH + tid];
        sh_qk[tid] = s * 0.17677669529663687f;
    }
    __syncthreads();

    const float kq0 = sh_qk[q8 * 4 + 0];
    const float kq1 = sh_qk[q8 * 4 + 1];
    const float kq2 = sh_qk[q8 * 4 + 2];
    const float kq3 = sh_qk[q8 * 4 + 3];

    const float* base = ne + (size_t)b * (NN * HH) + (size_t)r * HH + q8 * 4;

    // ---- raw dot products into LDS ----
    #pragma unroll 8
    for (int i = 0; i < NN / 64; ++i) {               // 64 iters
        const float4 v = *reinterpret_cast<const float4*>(base + i * (64 * HH));
        float p = v.x * kq0 + v.y * kq1 + v.z * kq2 + v.w * kq3;
        p += __shfl_xor(p, 1);
        p += __shfl_xor(p, 2);
        p += __shfl_xor(p, 4);
        if (q8 == 0) s_scores[r + i * 64] = p;
    }
    __syncthreads();

    // ---- apply mask (coalesced), block max ----
    const float* mrow = mask + (size_t)b * NN;
    float lmax = -INFINITY;
    #pragma unroll
    for (int k = 0; k < NN / T3; ++k) {
        const int n = tid + k * T3;
        const float sc = s_scores[n] - mrow[n] * 999999999.0f;
        s_scores[n] = sc;
        lmax = fmaxf(lmax, sc);
    }
    #pragma unroll
    for (int m = 1; m < 64; m <<= 1) lmax = fmaxf(lmax, __shfl_xor(lmax, m));
    if ((tid & 63) == 0) red_buf[tid >> 6] = lmax;
    __syncthreads();
    float bmax = red_buf[0];
    #pragma unroll
    for (int w = 1; w < 8; ++w) bmax = fmaxf(bmax, red_buf[w]);

    // ---- exp + sum ----
    float lsum = 0.f;
    #pragma unroll
    for (int k = 0; k < NN / T3; ++k) {
        const int n = tid + k * T3;
        const float e = expf(s_scores[n] - bmax);
        s_scores[n] = e;
        lsum += e;
    }
    #pragma unroll
    for (int m = 1; m < 64; m <<= 1) lsum += __shfl_xor(lsum, m);
    __syncthreads();                       // red_buf (max) reads done
    if ((tid & 63) == 0) red_buf[tid >> 6] = lsum;
    __syncthreads();
    float tot = red_buf[0];
    #pragma unroll
    for (int w = 1; w < 8; ++w) tot += red_buf[w];
    const float inv = 1.0f / tot;

    float* orow = out + (size_t)b * NN;
    #pragma unroll
    for (int k = 0; k < NN / T3; ++k) {
        const int n = tid + k * T3;
        orow[n] = s_scores[n] * inv;
    }
}

extern "C" void kernel_launch(void* const* d_in, const int* in_sizes, int n_in,
                              void* d_out, int out_size, void* d_ws, size_t ws_size,
                              hipStream_t stream) {
    (void)in_sizes; (void)n_in; (void)ws_size; (void)out_size;
    const float* ne    = (const float*)d_in[0];
    const float* mask  = (const float*)d_in[1];
    const float* times = (const float*)d_in[2];
    // d_in[3] = vf, unused (idxc path taken)
    const float* W1    = (const float*)d_in[4];
    const float* b1    = (const float*)d_in[5];
    const float* Wq    = (const float*)d_in[6];
    const float* Wk    = (const float*)d_in[7];
    const int*   idxc  = (const int*)d_in[8];
    float* out = (float*)d_out;
    float* ws  = (float*)d_ws;

    k1_colsum<<<dim3(BB * PP), dim3(256), 0, stream>>>(ne, ws);
    k3_scores<<<dim3(BB), dim3(T3), 0, stream>>>(
        ne, mask, times, W1, b1, Wq, Wk, idxc, ws, out);
}